// Round 1
// baseline (341.582 us; speedup 1.0000x reference)
//
#include <hip/hip_runtime.h>

#define Bsz 512
#define Nn  128
#define Dd  256
#define Tt  512

__device__ __forceinline__ float wave_reduce(float v) {
#pragma unroll
    for (int off = 32; off > 0; off >>= 1)
        v += __shfl_down(v, off, 64);
    return v;  // valid in lane 0
}

// One block per batch. Computes S (row-L1-normalized gated norm_adj) into ws.
__global__ __launch_bounds__(256) void prep_kernel(
    const float* __restrict__ x, const float* __restrict__ adj,
    const int* __restrict__ head, const float* __restrict__ lin_w,
    const float* __restrict__ bias, float* __restrict__ S)
{
    const int b = blockIdx.x;
    __shared__ float adjS[Nn][Nn + 1];
    __shared__ float dis[Nn], tt[Nn], alphaS[Nn], u[Nn], rowc[Nn], maskS[Nn];
    __shared__ int   flags[Nn];
    __shared__ int   nuniq_s;
    __shared__ float cut_s;

    const int tid  = threadIdx.x;
    const int lane = tid & 63;
    const int wv   = tid >> 6;          // 0..3
    const float bias0 = bias[0];

    if (tid < Nn) flags[tid] = 0;
    if (tid == 0) { nuniq_s = 0; cut_s = 0.0f; }
    __syncthreads();

    // ---- load adj tile to LDS (coalesced float4) ----
    const float* adjb = adj + (size_t)b * (Nn * Nn);
    const float4* adjb4 = (const float4*)adjb;
    for (int f = tid; f < (Nn * Nn) / 4; f += 256) {
        float4 v = adjb4[f];
        int r = f >> 5;             // 32 float4 per row
        int c = (f & 31) << 2;
        adjS[r][c]     = v.x; adjS[r][c + 1] = v.y;
        adjS[r][c + 2] = v.z; adjS[r][c + 3] = v.w;
    }

    // ---- head presence bitmap ----
    for (int t = tid; t < Tt; t += 256) {
        int h = head[(size_t)b * Tt + t];
        flags[h] = 1;
    }

    // ---- lin(x): wave-per-row dot over D=256 ----
    {
        const float lw0 = lin_w[lane];
        const float lw1 = lin_w[lane + 64];
        const float lw2 = lin_w[lane + 128];
        const float lw3 = lin_w[lane + 192];
        for (int n = wv; n < Nn; n += 4) {
            const float* xr = x + ((size_t)b * Nn + n) * Dd;
            float v = xr[lane] * lw0 + xr[lane + 64] * lw1
                    + xr[lane + 128] * lw2 + xr[lane + 192] * lw3;
            v = wave_reduce(v);
            if (lane == 0) tt[n] = v;   // raw lin_out for now
        }
    }
    __syncthreads();

    // ---- row sums -> dis, mask ; count uniques ----
    for (int n = wv; n < Nn; n += 4) {
        float v = adjS[n][lane] + adjS[n][lane + 64];
        v = wave_reduce(v);
        if (lane == 0) {
            maskS[n] = (v > 0.0f) ? 1.0f : 0.0f;
            dis[n]   = 1.0f / sqrtf(fmaxf(v + 1.0f, 1.0f));
        }
    }
    if (tid < Nn) atomicAdd(&nuniq_s, flags[tid]);
    __syncthreads();

    if (tid < Nn) tt[tid] *= dis[tid];   // tt[j] = dis_j * lin_j
    __syncthreads();

    // ---- alpha = sigmoid((mask_n dis_n * (sum_j adj_nj tt_j + tt_n) + bias)^2) ----
    for (int n = wv; n < Nn; n += 4) {
        float v = adjS[n][lane] * tt[lane] + adjS[n][lane + 64] * tt[lane + 64];
        v = wave_reduce(v);
        if (lane == 0) {
            float o = maskS[n] * dis[n] * (v + tt[n]) + bias0;
            alphaS[n] = 1.0f / (1.0f + expf(-o * o));
        }
    }
    __syncthreads();

    // ---- cut = k-th largest alpha (rank selection, handles ties like sort) ----
    {
        int nu = nuniq_s;
        if (nu > 1 && tid < Nn) {
            int idx = (int)ceilf((float)nu * 0.1f);   // = clip(k-1, 0, N-1)
            if (idx > Nn - 1) idx = Nn - 1;
            float an = alphaS[tid];
            int cg = 0, ce = 0;
#pragma unroll 4
            for (int j = 0; j < Nn; ++j) {
                float aj = alphaS[j];
                cg += (aj > an);
                ce += (aj == an);
            }
            if (cg <= idx && idx < cg + ce) cut_s = an;
        }
    }
    __syncthreads();

    // ---- cut_alpha, u = cut_alpha * dis ----
    if (tid < Nn) {
        float ca = fmaxf(alphaS[tid] + 1e-7f - cut_s, 0.0f);
        u[tid] = ca * dis[tid];
    }
    __syncthreads();

    // ---- row L1 norms of S' and row coefficient ----
    for (int n = wv; n < Nn; n += 4) {
        float v = adjS[n][lane] * u[lane] + adjS[n][lane + 64] * u[lane + 64];
        v = wave_reduce(v);
        if (lane == 0) {
            float tot  = v + u[n];                  // + diagonal (A_nn includes +I)
            float rsum = maskS[n] * dis[n] * tot;   // all terms >= 0 -> equals |S|.sum
            rowc[n] = maskS[n] * dis[n] / fmaxf(rsum, 1e-12f);
        }
    }
    __syncthreads();

    // ---- write S[b][r][c] = rowc_r * (adj_rc + delta_rc) * u_c ----
    float4* Sout4 = (float4*)(S + (size_t)b * (Nn * Nn));
    for (int f = tid; f < (Nn * Nn) / 4; f += 256) {
        int r = f >> 5;
        int c = (f & 31) << 2;
        float rc = rowc[r];
        float4 v;
        v.x = rc * (adjS[r][c]     + ((r == c)     ? 1.0f : 0.0f)) * u[c];
        v.y = rc * (adjS[r][c + 1] + ((r == c + 1) ? 1.0f : 0.0f)) * u[c + 1];
        v.z = rc * (adjS[r][c + 2] + ((r == c + 2) ? 1.0f : 0.0f)) * u[c + 2];
        v.w = rc * (adjS[r][c + 3] + ((r == c + 3) ? 1.0f : 0.0f)) * u[c + 3];
        Sout4[f] = v;
    }
}

// C[b][i][j] = sum_m A[b][m][i] * Bm[b][m][d0+j]   (A is k-major: 128x128)
// grid: (ldb/128, B), 256 threads, 8x8 register tile per thread.
__global__ __launch_bounds__(256) void ktk_gemm(
    const float* __restrict__ A, const float* __restrict__ Bm,
    float* __restrict__ C, int ldb)
{
    const int b  = blockIdx.y;
    const int d0 = blockIdx.x * 128;
    __shared__ float As[32][128];
    __shared__ float Bs[32][128];
    const int tid = threadIdx.x;
    const int ti  = tid & 15;
    const int td  = tid >> 4;

    float acc[8][8];
#pragma unroll
    for (int i = 0; i < 8; ++i)
#pragma unroll
        for (int j = 0; j < 8; ++j) acc[i][j] = 0.0f;

    const float* Ab = A  + (size_t)b * (128 * 128);
    const float* Bb = Bm + (size_t)b * 128 * ldb;

    for (int m0 = 0; m0 < 128; m0 += 32) {
#pragma unroll
        for (int r = 0; r < 4; ++r) {
            int f  = tid + 256 * r;       // float4 index, 0..1023
            int mm = f >> 5;
            int c  = (f & 31) << 2;
            *(float4*)&As[mm][c] = *(const float4*)&Ab[(size_t)(m0 + mm) * 128 + c];
            *(float4*)&Bs[mm][c] = *(const float4*)&Bb[(size_t)(m0 + mm) * ldb + d0 + c];
        }
        __syncthreads();
#pragma unroll
        for (int mm = 0; mm < 32; ++mm) {
            float a[8], bb[8];
            *(float4*)&a[0]  = *(float4*)&As[mm][ti * 8];
            *(float4*)&a[4]  = *(float4*)&As[mm][ti * 8 + 4];
            *(float4*)&bb[0] = *(float4*)&Bs[mm][td * 8];
            *(float4*)&bb[4] = *(float4*)&Bs[mm][td * 8 + 4];
#pragma unroll
            for (int i = 0; i < 8; ++i)
#pragma unroll
                for (int j = 0; j < 8; ++j)
                    acc[i][j] = fmaf(a[i], bb[j], acc[i][j]);
        }
        __syncthreads();
    }

#pragma unroll
    for (int i = 0; i < 8; ++i) {
        int row = ti * 8 + i;
        float* outr = C + ((size_t)b * 128 + row) * ldb + d0 + td * 8;
        float4 v0 = { acc[i][0], acc[i][1], acc[i][2], acc[i][3] };
        float4 v1 = { acc[i][4], acc[i][5], acc[i][6], acc[i][7] };
        *(float4*)outr       = v0;
        *(float4*)(outr + 4) = v1;
    }
}

// P[b][m][j] = sum_k adj[b][m][k] * S[b][k][j]   (adj is m-major)
__global__ __launch_bounds__(256) void adj_s_gemm(
    const float* __restrict__ adj, const float* __restrict__ S,
    float* __restrict__ P)
{
    const int b = blockIdx.x;
    __shared__ float As[128][33];   // As[m][kk]
    __shared__ float Bs[32][128];   // Bs[kk][j]
    const int tid = threadIdx.x;
    const int tm  = tid & 15;
    const int tj  = tid >> 4;

    float acc[8][8];
#pragma unroll
    for (int i = 0; i < 8; ++i)
#pragma unroll
        for (int j = 0; j < 8; ++j) acc[i][j] = 0.0f;

    const float* adjb = adj + (size_t)b * (128 * 128);
    const float* Sb   = S   + (size_t)b * (128 * 128);

    for (int k0 = 0; k0 < 128; k0 += 32) {
#pragma unroll
        for (int r = 0; r < 4; ++r) {
            int f = tid + 256 * r;        // float4 index over 128x8
            int m = f >> 3;
            int c = (f & 7) << 2;
            float4 v = *(const float4*)&adjb[(size_t)m * 128 + k0 + c];
            As[m][c]     = v.x; As[m][c + 1] = v.y;
            As[m][c + 2] = v.z; As[m][c + 3] = v.w;
            int mm = f >> 5;
            int cc = (f & 31) << 2;
            *(float4*)&Bs[mm][cc] = *(const float4*)&Sb[(size_t)(k0 + mm) * 128 + cc];
        }
        __syncthreads();
#pragma unroll
        for (int kk = 0; kk < 32; ++kk) {
            float bb[8];
            *(float4*)&bb[0] = *(float4*)&Bs[kk][tj * 8];
            *(float4*)&bb[4] = *(float4*)&Bs[kk][tj * 8 + 4];
            float a[8];
#pragma unroll
            for (int i = 0; i < 8; ++i) a[i] = As[tm * 8 + i][kk];
#pragma unroll
            for (int i = 0; i < 8; ++i)
#pragma unroll
                for (int j = 0; j < 8; ++j)
                    acc[i][j] = fmaf(a[i], bb[j], acc[i][j]);
        }
        __syncthreads();
    }

#pragma unroll
    for (int i = 0; i < 8; ++i) {
        int row = tm * 8 + i;
        float* outr = P + ((size_t)b * 128 + row) * 128 + tj * 8;
        float4 v0 = { acc[i][0], acc[i][1], acc[i][2], acc[i][3] };
        float4 v1 = { acc[i][4], acc[i][5], acc[i][6], acc[i][7] };
        *(float4*)outr       = v0;
        *(float4*)(outr + 4) = v1;
    }
}

extern "C" void kernel_launch(void* const* d_in, const int* in_sizes, int n_in,
                              void* d_out, int out_size, void* d_ws, size_t ws_size,
                              hipStream_t stream)
{
    const float* x     = (const float*)d_in[0];
    const float* adj   = (const float*)d_in[1];
    const int*   head  = (const int*)d_in[2];
    const float* lin_w = (const float*)d_in[3];
    const float* bias  = (const float*)d_in[4];

    float* emb  = (float*)d_out;                       // [B,N,D]
    float* nadj = emb + (size_t)Bsz * Nn * Dd;         // [B,N,N]

    float* S = (float*)d_ws;                           // [B,N,N]
    float* P = S + (size_t)Bsz * Nn * Nn;              // [B,N,N]

    // 1) build S
    prep_kernel<<<Bsz, 256, 0, stream>>>(x, adj, head, lin_w, bias, S);
    // 2) emb = S^T x
    ktk_gemm<<<dim3(2, Bsz), 256, 0, stream>>>(S, x, emb, Dd);
    // 3) P = adj @ S
    adj_s_gemm<<<Bsz, 256, 0, stream>>>(adj, S, P);
    // 4) new_adj = S^T P
    ktk_gemm<<<dim3(1, Bsz), 256, 0, stream>>>(S, P, nadj, Nn);
}

// Round 2
// 230.565 us; speedup vs baseline: 1.4815x; 1.4815x over previous
//
#include <hip/hip_runtime.h>

#define Bsz 512
#define Nn  128
#define Dd  256
#define Tt  512

typedef __attribute__((ext_vector_type(8))) short short8;
typedef __attribute__((ext_vector_type(4))) float f32x4;

__device__ __forceinline__ ushort f2bf(float f) {
    union { float f; unsigned u; } v; v.f = f;
    unsigned r = v.u + 0x7fffu + ((v.u >> 16) & 1u);  // RNE
    return (ushort)(r >> 16);
}
__device__ __forceinline__ unsigned pk2(float a, float b) {
    return (unsigned)f2bf(a) | ((unsigned)f2bf(b) << 16);
}

// ---------------------------------------------------------------------------
// xprep: stream x once -> lin-dot partials (dotv2) + transposed bf16 xT[b][d][k]
// grid (2, B): blockIdx.x = d-half. LDS transpose buffer stride 130 -> scatter
// writes land 2-way (free); reads are uniform 4/bank (b64 minimum).
// ---------------------------------------------------------------------------
__global__ __launch_bounds__(256) void xprep(
    const float* __restrict__ x, const float* __restrict__ lin_w,
    float* __restrict__ dotv2, ushort* __restrict__ xT)
{
    const int h = blockIdx.x, b = blockIdx.y;
    __shared__ float xbufT[32][130];
    __shared__ float pdot[128][8];
    __shared__ float wS[128];
    const int t = threadIdx.x;
    if (t < 128) wS[t] = lin_w[h * 128 + t];
    const int c4 = t & 7;          // d-slot (x4 floats)
    const int kb = t >> 3;         // 0..31
    const int kc = t & 15, dsub = t >> 4;
    float p[4] = {0.f, 0.f, 0.f, 0.f};
    __syncthreads();

    for (int c = 0; c < 4; ++c) {                 // 4 chunks of 32 dims
        const int dl = 4 * c4;
        float4 v[4];
#pragma unroll
        for (int i = 0; i < 4; ++i)
            v[i] = *(const float4*)&x[((size_t)b * Nn + (kb + 32 * i)) * Dd
                                      + h * 128 + c * 32 + dl];
        const float w0 = wS[c*32+dl],   w1 = wS[c*32+dl+1];
        const float w2 = wS[c*32+dl+2], w3 = wS[c*32+dl+3];
#pragma unroll
        for (int i = 0; i < 4; ++i) {
            p[i] += v[i].x*w0 + v[i].y*w1 + v[i].z*w2 + v[i].w*w3;
            xbufT[dl    ][kb + 32*i] = v[i].x;
            xbufT[dl + 1][kb + 32*i] = v[i].y;
            xbufT[dl + 2][kb + 32*i] = v[i].z;
            xbufT[dl + 3][kb + 32*i] = v[i].w;
        }
        __syncthreads();
#pragma unroll
        for (int pp = 0; pp < 2; ++pp) {
            int d = dsub + 16 * pp;
            float2 q0 = *(float2*)&xbufT[d][kc*8 + 0];
            float2 q1 = *(float2*)&xbufT[d][kc*8 + 2];
            float2 q2 = *(float2*)&xbufT[d][kc*8 + 4];
            float2 q3 = *(float2*)&xbufT[d][kc*8 + 6];
            uint4 pkv;
            pkv.x = pk2(q0.x, q0.y);
            pkv.y = pk2(q1.x, q1.y);
            pkv.z = pk2(q2.x, q2.y);
            pkv.w = pk2(q3.x, q3.y);
            *(uint4*)&xT[((size_t)b * Dd + h * 128 + c * 32 + d) * Nn + kc * 8] = pkv;
        }
        __syncthreads();
    }
#pragma unroll
    for (int i = 0; i < 4; ++i) pdot[kb + 32*i][c4] = p[i];
    __syncthreads();
    if (t < 128) {
        float s = 0.f;
#pragma unroll
        for (int j = 0; j < 8; ++j) s += pdot[t][j];
        dotv2[((size_t)b * Nn + t) * 2 + h] = s;
    }
}

// ---------------------------------------------------------------------------
// sprep: one block per batch. adj staged fp32 in LDS (pad 132: row passes and
// column passes both ~2-way = free). Per-thread half-row serial reductions
// (no shuffle chains). Writes ST[b][m][k] = S[k][m] in bf16.
// ---------------------------------------------------------------------------
__global__ __launch_bounds__(256) void sprep(
    const float* __restrict__ adj, const int* __restrict__ head,
    const float* __restrict__ dotv2, const float* __restrict__ bias,
    ushort* __restrict__ STbf)
{
    const int b = blockIdx.x;
    __shared__ __align__(16) float adjS[Nn][132];
    __shared__ __align__(16) float ttS[Nn], disS[Nn], maskS[Nn],
                                   alphaS[Nn], uS[Nn], rowcS[Nn];
    __shared__ float partS[Nn][2];
    __shared__ int   flags[Nn];
    __shared__ int   nuniq_s;
    __shared__ float cut_s;

    const int t = threadIdx.x;
    const float bias0 = bias[0];
    if (t < Nn) flags[t] = 0;
    if (t == 0) { nuniq_s = 0; cut_s = 0.f; }

    const float* adjb = adj + (size_t)b * (Nn * Nn);
#pragma unroll
    for (int i = 0; i < 16; ++i) {
        int f = t + 256 * i;
        int rr = f >> 5, c = (f & 31) * 4;
        *(float4*)&adjS[rr][c] = *(const float4*)&adjb[rr * Nn + c];
    }
    __syncthreads();

    { // head presence
        int h0 = head[(size_t)b * Tt + t];
        int h1 = head[(size_t)b * Tt + 256 + t];
        flags[h0] = 1; flags[h1] = 1;
    }

    const int r = t >> 1, hh = t & 1, base = hh * 64;
    { // row sums
        float4 s4 = {0.f, 0.f, 0.f, 0.f};
#pragma unroll
        for (int j = 0; j < 16; ++j) {
            float4 v = *(float4*)&adjS[r][base + 4*j];
            s4.x += v.x; s4.y += v.y; s4.z += v.z; s4.w += v.w;
        }
        partS[r][hh] = (s4.x + s4.y) + (s4.z + s4.w);
    }
    __syncthreads();
    if (t < Nn) {
        float rs  = partS[t][0] + partS[t][1];
        float m   = (rs > 0.f) ? 1.f : 0.f;
        float dis = 1.f / sqrtf(fmaxf(rs + 1.f, 1.f));
        maskS[t] = m; disS[t] = dis;
        float lin = dotv2[((size_t)b * Nn + t) * 2]
                  + dotv2[((size_t)b * Nn + t) * 2 + 1];
        ttS[t] = dis * lin;
        atomicAdd(&nuniq_s, flags[t]);
    }
    __syncthreads();
    { // matvec adj * tt
        float4 a = {0.f, 0.f, 0.f, 0.f};
#pragma unroll
        for (int j = 0; j < 16; ++j) {
            float4 v = *(float4*)&adjS[r][base + 4*j];
            float4 w = *(float4*)&ttS[base + 4*j];
            a.x += v.x*w.x; a.y += v.y*w.y; a.z += v.z*w.z; a.w += v.w*w.w;
        }
        partS[r][hh] = (a.x + a.y) + (a.z + a.w);
    }
    __syncthreads();
    if (t < Nn) {
        float mv = partS[t][0] + partS[t][1];
        float o  = maskS[t] * disS[t] * (mv + ttS[t]) + bias0;
        alphaS[t] = 1.f / (1.f + expf(-o * o));
    }
    __syncthreads();
    if (t < Nn) { // exact k-th-largest via rank selection (ties == sort)
        int nu = nuniq_s;
        if (nu > 1) {
            int idx = (int)ceilf((float)nu * 0.1f);
            if (idx > Nn - 1) idx = Nn - 1;
            float an = alphaS[t];
            int cg = 0, ce = 0;
            for (int j = 0; j < Nn; ++j) {
                float aj = alphaS[j];
                cg += (aj > an); ce += (aj == an);
            }
            if (cg <= idx && idx < cg + ce) cut_s = an;  // benign same-value race
        }
    }
    __syncthreads();
    if (t < Nn) uS[t] = fmaxf(alphaS[t] + 1e-7f - cut_s, 0.f) * disS[t];
    __syncthreads();
    { // matvec adj * u  (row L1 norm, all terms >= 0)
        float4 a = {0.f, 0.f, 0.f, 0.f};
#pragma unroll
        for (int j = 0; j < 16; ++j) {
            float4 v = *(float4*)&adjS[r][base + 4*j];
            float4 w = *(float4*)&uS[base + 4*j];
            a.x += v.x*w.x; a.y += v.y*w.y; a.z += v.z*w.z; a.w += v.w*w.w;
        }
        partS[r][hh] = (a.x + a.y) + (a.z + a.w);
    }
    __syncthreads();
    if (t < Nn) {
        float tot  = partS[t][0] + partS[t][1] + uS[t];
        float rsum = maskS[t] * disS[t] * tot;
        rowcS[t] = maskS[t] * disS[t] / fmaxf(rsum, 1e-12f);
    }
    __syncthreads();
    { // ST[m][k] = rowc_k * (adj[k][m] + delta) * u_m  (bf16, 16B stores)
        const float um = uS[r];
        ushort* outp = STbf + ((size_t)b * Nn + r) * Nn + base;
#pragma unroll
        for (int kcc = 0; kcc < 8; ++kcc) {
            int k0 = base + kcc * 8;
            float vv[8];
#pragma unroll
            for (int j = 0; j < 8; ++j) {
                int k = k0 + j;
                vv[j] = rowcS[k] * (adjS[k][r] + ((k == r) ? 1.f : 0.f)) * um;
            }
            uint4 pkv;
            pkv.x = pk2(vv[0], vv[1]); pkv.y = pk2(vv[2], vv[3]);
            pkv.z = pk2(vv[4], vv[5]); pkv.w = pk2(vv[6], vv[7]);
            *(uint4*)(outp + kcc * 8) = pkv;
        }
    }
}

// ---------------------------------------------------------------------------
// emb = S^T x via mfma 16x16x32 bf16. A = ST[m][k], B = xT[n=d][k], both
// staged [row][k] with +8 bf16 pad (stride 136 -> 16B-aligned, 2-way banks).
// grid (2, B): blockIdx.x = d-half.
// ---------------------------------------------------------------------------
__global__ __launch_bounds__(256, 2) void emb_gemm(
    const ushort* __restrict__ STbf, const ushort* __restrict__ xT,
    float* __restrict__ emb)
{
    const int d0 = blockIdx.x * 128;
    const int b  = blockIdx.y;
    __shared__ ushort STl[128][136];
    __shared__ ushort xTl[128][136];
    const int t = threadIdx.x;
    const uint4* sg = (const uint4*)(STbf + (size_t)b * Nn * Nn);
    const uint4* xg = (const uint4*)(xT + ((size_t)b * Dd + d0) * Nn);
#pragma unroll
    for (int i = 0; i < 8; ++i) {
        int f = t + 256 * i;               // 16B-chunk id, 0..2047
        int row = f >> 4, c8 = f & 15;
        *(uint4*)&STl[row][c8 * 8] = sg[f];
        *(uint4*)&xTl[row][c8 * 8] = xg[f];
    }
    __syncthreads();

    const int lane = t & 63, wv = t >> 6;
    const int l15 = lane & 15, quad = lane >> 4;
    const int m0 = wv * 32;
    f32x4 acc[2][8];
#pragma unroll
    for (int mt = 0; mt < 2; ++mt)
#pragma unroll
        for (int nt = 0; nt < 8; ++nt) acc[mt][nt] = (f32x4){0.f, 0.f, 0.f, 0.f};

#pragma unroll
    for (int k0 = 0; k0 < 128; k0 += 32) {
        short8 a0 = *(const short8*)&STl[m0 + l15][k0 + quad * 8];
        short8 a1 = *(const short8*)&STl[m0 + 16 + l15][k0 + quad * 8];
        short8 bf[8];
#pragma unroll
        for (int nt = 0; nt < 8; ++nt)
            bf[nt] = *(const short8*)&xTl[nt * 16 + l15][k0 + quad * 8];
#pragma unroll
        for (int nt = 0; nt < 8; ++nt) {
            acc[0][nt] = __builtin_amdgcn_mfma_f32_16x16x32_bf16(a0, bf[nt], acc[0][nt], 0, 0, 0);
            acc[1][nt] = __builtin_amdgcn_mfma_f32_16x16x32_bf16(a1, bf[nt], acc[1][nt], 0, 0, 0);
        }
    }
#pragma unroll
    for (int mt = 0; mt < 2; ++mt)
#pragma unroll
        for (int nt = 0; nt < 8; ++nt)
#pragma unroll
            for (int rr = 0; rr < 4; ++rr) {
                int row = m0 + mt * 16 + quad * 4 + rr;   // C: row = quad*4+reg
                int col = d0 + nt * 16 + l15;             //    col = lane&15
                emb[((size_t)b * Nn + row) * Dd + col] = acc[mt][nt][rr];
            }
}

// ---------------------------------------------------------------------------
// Fused new_adj = S^T (A S): G2 computes P = A*S (A = adj bf16), writes P^T
// back into A's LDS buffer (dead after G2), then G3 computes S^T P. No HBM
// round-trip for P. LDS 68KB -> 2 blocks/CU.
// ---------------------------------------------------------------------------
__global__ __launch_bounds__(256, 2) void padj_gemm(
    const float* __restrict__ adj, const ushort* __restrict__ STbf,
    float* __restrict__ nadj)
{
    const int b = blockIdx.x;
    __shared__ ushort bufA[128][136];   // adj bf16, then P^T
    __shared__ ushort STl[128][136];
    const int t = threadIdx.x;

    const float* adjb = adj + (size_t)b * Nn * Nn;
#pragma unroll
    for (int i = 0; i < 16; ++i) {
        int f = t + 256 * i;            // float4 id, 0..4095
        int rr = f >> 5, c4 = f & 31;
        float4 v = *(const float4*)&adjb[rr * Nn + c4 * 4];
        uint2 w; w.x = pk2(v.x, v.y); w.y = pk2(v.z, v.w);
        *(uint2*)&bufA[rr][c4 * 4] = w;
    }
    const uint4* sg = (const uint4*)(STbf + (size_t)b * Nn * Nn);
#pragma unroll
    for (int i = 0; i < 8; ++i) {
        int f = t + 256 * i;
        *(uint4*)&STl[f >> 4][(f & 15) * 8] = sg[f];
    }
    __syncthreads();

    const int lane = t & 63, wv = t >> 6;
    const int l15 = lane & 15, quad = lane >> 4;
    const int m0 = wv * 32;
    f32x4 acc[2][8];
#pragma unroll
    for (int mt = 0; mt < 2; ++mt)
#pragma unroll
        for (int nt = 0; nt < 8; ++nt) acc[mt][nt] = (f32x4){0.f, 0.f, 0.f, 0.f};

    // ---- G2: P = adj * S ----
#pragma unroll
    for (int k0 = 0; k0 < 128; k0 += 32) {
        short8 a0 = *(const short8*)&bufA[m0 + l15][k0 + quad * 8];
        short8 a1 = *(const short8*)&bufA[m0 + 16 + l15][k0 + quad * 8];
        short8 bf[8];
#pragma unroll
        for (int nt = 0; nt < 8; ++nt)
            bf[nt] = *(const short8*)&STl[nt * 16 + l15][k0 + quad * 8];
#pragma unroll
        for (int nt = 0; nt < 8; ++nt) {
            acc[0][nt] = __builtin_amdgcn_mfma_f32_16x16x32_bf16(a0, bf[nt], acc[0][nt], 0, 0, 0);
            acc[1][nt] = __builtin_amdgcn_mfma_f32_16x16x32_bf16(a1, bf[nt], acc[1][nt], 0, 0, 0);
        }
    }
    __syncthreads();   // all waves done reading bufA
    // ---- write P^T[j][m] into bufA (4 consecutive m per lane -> b64) ----
#pragma unroll
    for (int mt = 0; mt < 2; ++mt)
#pragma unroll
        for (int nt = 0; nt < 8; ++nt) {
            int j    = nt * 16 + l15;
            int mcol = m0 + mt * 16 + quad * 4;
            uint2 w;
            w.x = pk2(acc[mt][nt][0], acc[mt][nt][1]);
            w.y = pk2(acc[mt][nt][2], acc[mt][nt][3]);
            *(uint2*)&bufA[j][mcol] = w;
        }
    __syncthreads();

#pragma unroll
    for (int mt = 0; mt < 2; ++mt)
#pragma unroll
        for (int nt = 0; nt < 8; ++nt) acc[mt][nt] = (f32x4){0.f, 0.f, 0.f, 0.f};

    // ---- G3: nadj = S^T P  (A = ST, B = P^T) ----
#pragma unroll
    for (int k0 = 0; k0 < 128; k0 += 32) {
        short8 a0 = *(const short8*)&STl[m0 + l15][k0 + quad * 8];
        short8 a1 = *(const short8*)&STl[m0 + 16 + l15][k0 + quad * 8];
        short8 bf[8];
#pragma unroll
        for (int nt = 0; nt < 8; ++nt)
            bf[nt] = *(const short8*)&bufA[nt * 16 + l15][k0 + quad * 8];
#pragma unroll
        for (int nt = 0; nt < 8; ++nt) {
            acc[0][nt] = __builtin_amdgcn_mfma_f32_16x16x32_bf16(a0, bf[nt], acc[0][nt], 0, 0, 0);
            acc[1][nt] = __builtin_amdgcn_mfma_f32_16x16x32_bf16(a1, bf[nt], acc[1][nt], 0, 0, 0);
        }
    }
#pragma unroll
    for (int mt = 0; mt < 2; ++mt)
#pragma unroll
        for (int nt = 0; nt < 8; ++nt)
#pragma unroll
            for (int rr = 0; rr < 4; ++rr) {
                int row = m0 + mt * 16 + quad * 4 + rr;
                int col = nt * 16 + l15;
                nadj[((size_t)b * Nn + row) * Nn + col] = acc[mt][nt][rr];
            }
}

extern "C" void kernel_launch(void* const* d_in, const int* in_sizes, int n_in,
                              void* d_out, int out_size, void* d_ws, size_t ws_size,
                              hipStream_t stream)
{
    const float* x     = (const float*)d_in[0];
    const float* adj   = (const float*)d_in[1];
    const int*   head  = (const int*)d_in[2];
    const float* lin_w = (const float*)d_in[3];
    const float* bias  = (const float*)d_in[4];

    float* emb  = (float*)d_out;                         // [B,N,D]
    float* nadj = emb + (size_t)Bsz * Nn * Dd;           // [B,N,N]

    ushort* STbf = (ushort*)d_ws;                        // [B,N,N] bf16 (S^T)
    ushort* xT   = STbf + (size_t)Bsz * Nn * Nn;         // [B,D,N] bf16 (x^T)
    float*  dotv2 = (float*)(xT + (size_t)Bsz * Dd * Nn);// [B,N,2]

    xprep<<<dim3(2, Bsz), 256, 0, stream>>>(x, lin_w, dotv2, xT);
    sprep<<<Bsz, 256, 0, stream>>>(adj, head, dotv2, bias, STbf);
    emb_gemm<<<dim3(2, Bsz), 256, 0, stream>>>(STbf, xT, emb);
    padj_gemm<<<Bsz, 256, 0, stream>>>(adj, STbf, nadj);
}